// Round 15
// baseline (219.473 us; speedup 1.0000x reference)
//
#include <hip/hip_runtime.h>
#include <hip/hip_fp16.h>
#include <math.h>

constexpr int N_ENT = 20000;
constexpr int N_REL = 500;
constexpr int NE    = 300000;   // entity triplets
constexpr int NER   = 50000;    // relation triplets
constexpr int MPE   = 20096;    // 157*128 (padded entity rows)
constexpr int CAPE  = 64;       // per-entity edge bucket capacity (Poisson(15))
constexpr int CAPR  = 192;      // per-relation edge bucket capacity (Poisson(100))
constexpr float EPSF = 1e-16f;

__device__ __forceinline__ float leaky(float x) { return x > 0.f ? x : 0.2f * x; }

typedef __attribute__((ext_vector_type(8))) _Float16 f16x8;
typedef __attribute__((ext_vector_type(4))) _Float16 f16x4;
typedef __attribute__((ext_vector_type(4))) float f32x4;

__device__ __forceinline__ float bp1val(const float* Wa, const float* Wg,
                                        const float* Wr, int row, int k) {
    if (row < 128) return Wa[row * 320 + k];
    if (row < 384) {
        int m = row - 128;
        int c = 4 * (m >> 3) + (m & 3);
        return ((m & 4) == 0) ? Wa[c * 320 + 128 + k] : Wg[c * 192 + k];
    }
    return Wr[(row - 384) * 128 + k];
}
__device__ __forceinline__ float bp3val(const float* Wa, const float* Wg,
                                        const float* Wr, int row, int k) {
    if (row < 64) return Wa[row * 128 + k];
    if (row < 128) return Wa[(row - 64) * 128 + 64 + k];
    if (row < 192) return Wg[(row - 128) * 64 + k];
    return Wr[(row - 192) * 64 + k];
}

// ---------------------------------------------------------------- MFMA fp16 GEMM (used for l=1 E16 only)
__global__ __launch_bounds__(256) void k_hgemm(
    const _Float16* __restrict__ A,
    const _Float16* __restrict__ B,
    const float* __restrict__ bias,
    __half* __restrict__ O16, float* __restrict__ O32,
    int M, int N, int K, int ldo)
{
    __shared__ __align__(16) _Float16 lA[4 * 128 * 8];
    __shared__ __align__(16) _Float16 lB[4 * 64 * 8];
    int tid = threadIdx.x;
    int m0 = blockIdx.y * 128, n0 = blockIdx.x * 64;
    int l = tid & 63, w = tid >> 6;
    int wr = w >> 1, wc = w & 1;
    int kq = l >> 4, lr = l & 15;

    int sA0 = tid, sA1 = tid + 256;
    const uint4* pA0 = (const uint4*)(A + (size_t)(m0 + (sA0 & 127)) * K) + (sA0 >> 7);
    const uint4* pA1 = (const uint4*)(A + (size_t)(m0 + (sA1 & 127)) * K) + (sA1 >> 7);
    const uint4* pB  = (const uint4*)(B + (size_t)(n0 + (tid & 63)) * K) + (tid >> 6);

    f32x4 acc[4][2] = {};
    int nk = K >> 5;
    uint4 va0 = pA0[0], va1 = pA1[0], vb = pB[0];
    for (int t = 0; t < nk; ++t) {
        ((uint4*)lA)[sA0] = va0;
        ((uint4*)lA)[sA1] = va1;
        ((uint4*)lB)[tid] = vb;
        __syncthreads();
        if (t + 1 < nk) {
            va0 = pA0[(t + 1) * 4];
            va1 = pA1[(t + 1) * 4];
            vb  = pB[(t + 1) * 4];
        }
        f16x8 bf0 = *(const f16x8*)&lB[(kq * 64 + wc * 32 + lr) * 8];
        f16x8 bf1 = *(const f16x8*)&lB[(kq * 64 + wc * 32 + 16 + lr) * 8];
#pragma unroll
        for (int fm = 0; fm < 4; ++fm) {
            f16x8 af = *(const f16x8*)&lA[(kq * 128 + wr * 64 + fm * 16 + lr) * 8];
            acc[fm][0] = __builtin_amdgcn_mfma_f32_16x16x32_f16(af, bf0, acc[fm][0], 0, 0, 0);
            acc[fm][1] = __builtin_amdgcn_mfma_f32_16x16x32_f16(af, bf1, acc[fm][1], 0, 0, 0);
        }
        __syncthreads();
    }
    int gn0 = n0 + wc * 32 + lr;
    int gn1 = gn0 + 16;
    float bc0 = (bias && gn0 < N) ? bias[gn0] : 0.f;
    float bc1 = (bias && gn1 < N) ? bias[gn1] : 0.f;
#pragma unroll
    for (int fm = 0; fm < 4; ++fm) {
#pragma unroll
        for (int j = 0; j < 4; ++j) {
            int gm = m0 + wr * 64 + fm * 16 + kq * 4 + j;
            if (gm >= M) continue;
            float v0 = acc[fm][0][j] + bc0;
            float v1 = acc[fm][1][j] + bc1;
            if (O16) {
                if (gn0 < N) O16[(size_t)gm * ldo + gn0] = __float2half_rn(v0);
                if (gn1 < N) O16[(size_t)gm * ldo + gn1] = __float2half_rn(v1);
            } else {
                if (gn0 < N) O32[(size_t)gm * ldo + gn0] = v0;
                if (gn1 < N) O32[(size_t)gm * ldo + gn1] = v1;
            }
        }
    }
}

// ---------------------------------------------------------------- mega-pack (grid: 640 blocks x 256)
__global__ void k_pack_all(
    const float* __restrict__ emb_ent, const float* __restrict__ emb_rel,
    const float* __restrict__ Wa_e, const float* __restrict__ ba_e,
    const float* __restrict__ Wg_e, const float* __restrict__ bg_e,
    const float* __restrict__ Wres_e, const float* __restrict__ bres_e,
    const float* __restrict__ Wa_r, const float* __restrict__ ba_r,
    const float* __restrict__ Wg_r, const float* __restrict__ bg_r,
    const float* __restrict__ Wres_r, const float* __restrict__ bres_r,
    const float* __restrict__ Wp1e, const float* __restrict__ p1b,
    const float* __restrict__ Wp1r, const float* __restrict__ p1rb,
    const float* __restrict__ Wp2e, const float* __restrict__ vec_e,
    _Float16* __restrict__ embh,
    _Float16* __restrict__ Bp1f, float* __restrict__ bias1,
    _Float16* __restrict__ Bp2f,
    float* __restrict__ Bp3, float* __restrict__ bias3,
    _Float16* __restrict__ Wcomph, float* __restrict__ biasC,
    float* __restrict__ AR,
    float* __restrict__ W2Tf,
    _Float16* __restrict__ vech,
    int* __restrict__ cnt)
{
    __shared__ float xsh[64];
    int gid = blockIdx.x * 256 + threadIdx.x;
    bool arblk = (blockIdx.x < N_REL);  // blocks 0..499 own AR row n = blockIdx.x
    if (arblk && threadIdx.x < 64) {    // hoisted intermediate x[d], shared per block
        int d = threadIdx.x;
        int n = blockIdx.x;
        float x = p1rb[d];
        for (int k = 0; k < 16; ++k)
            x = fmaf(emb_rel[n * 16 + k], Wp1r[d * 16 + k], x);
        xsh[d] = x;
    }
    __syncthreads();                    // uniform per block (all-in or all-out)
    if (arblk) {
        int n = blockIdx.x, j = threadIdx.x;
        float bb;
        if (j < 64) bb = ba_r[j];
        else if (j < 128) bb = 0.f;
        else if (j < 192) bb = bg_r[j - 128];
        else bb = bres_r[j - 192];
        float a0 = 0.f, a1 = 0.f;
        for (int d = 0; d < 64; d += 2) {
            a0 = fmaf(bp3val(Wa_r, Wg_r, Wres_r, j, d), xsh[d], a0);
            a1 = fmaf(bp3val(Wa_r, Wg_r, Wres_r, j, d + 1), xsh[d + 1], a1);
        }
        AR[n * 256 + j] = bb + a0 + a1;
    }
    if (gid * 4 < N_ENT * 32) {         // embh, 4-wide
        float4 e = *(const float4*)&emb_ent[gid * 4];
        f16x4 h = { (_Float16)e.x, (_Float16)e.y, (_Float16)e.z, (_Float16)e.w };
        *(f16x4*)&embh[gid * 4] = h;
    }
    const float* Wa1 = Wa_e + 128 * 320;
    const float* Wg1 = Wg_e + 128 * 192;
    const float* Wr1 = Wres_e + 128 * 128;
    if (gid < 512 * 128) {          // Bp1f l=1
        int row = gid >> 7, k = gid & 127;
        Bp1f[gid] = (_Float16)bp1val(Wa1, Wg1, Wr1, row, k);
    }
    if (gid < 512 * 64) {           // Bp2f[l*256 + m][64]
        int row = gid >> 6, k = gid & 63;
        int l = row >> 8, m = row & 255;
        int c = 4 * (m >> 3) + (m & 3);
        const float* Wa = Wa_e + (size_t)l * 128 * 320;
        const float* Wg = Wg_e + (size_t)l * 128 * 192;
        float v = ((m & 4) == 0) ? Wa[c * 320 + 256 + k] : Wg[c * 192 + 128 + k];
        Bp2f[gid] = (_Float16)v;
    }
    const float* Wa1r = Wa_r + 64 * 128;
    const float* Wg1r = Wg_r + 64 * 64;
    const float* Wr1r = Wres_r + 64 * 64;
    if (gid < 256 * 64) {           // Bp3 l=1
        int row = gid >> 6, k = gid & 63;
        Bp3[gid] = bp3val(Wa1r, Wg1r, Wr1r, row, k);
    }
    if (gid < 512 * 32) {           // Wcomp ent l0 = Bp1_l0 @ P1e
        int n = gid >> 5, j = gid & 31;
        float a = 0.f;
        for (int d = 0; d < 128; ++d)
            a += bp1val(Wa_e, Wg_e, Wres_e, n, d) * Wp1e[d * 32 + j];
        Wcomph[gid] = (_Float16)a;
    }
    if (gid < 512) {                // bias1 (l=1) and biasC (l=0 composed)
        int j = gid;
        float v;
        if (j < 128) v = ba_e[128 + j];
        else if (j < 384) {
            int m = j - 128, c = 4 * (m >> 3) + (m & 3);
            v = ((m & 4) == 0) ? 0.f : bg_e[128 + c];
        } else v = bres_e[128 + j - 384];
        bias1[j] = v;
        float v0;
        if (j < 128) v0 = ba_e[j];
        else if (j < 384) {
            int m = j - 128, c = 4 * (m >> 3) + (m & 3);
            v0 = ((m & 4) == 0) ? 0.f : bg_e[c];
        } else v0 = bres_e[j - 384];
        float a = v0;
        for (int d = 0; d < 128; ++d)
            a += bp1val(Wa_e, Wg_e, Wres_e, j, d) * p1b[d];
        biasC[j] = a;
    }
    if (gid < 256) {                // bias3 (rel l=1)
        int j = gid;
        float v;
        if (j < 64) v = ba_r[64 + j];
        else if (j < 128) v = 0.f;
        else if (j < 192) v = bg_r[64 + (j - 128)];
        else v = bres_r[64 + (j - 192)];
        bias3[j] = v;
    }
    if (gid < 128 * 32) {           // W2Tf[k][j] = ent_proj2_W[j][k]
        int k = gid >> 5, j = gid & 31;
        W2Tf[gid] = Wp2e[j * 128 + k];
    }
    if (gid < 2 * 128) vech[gid] = (_Float16)vec_e[gid];
    if (gid < N_ENT + N_REL) cnt[gid] = 0;
}

// ---------------------------------------------------------------- direct bucket scatter
__global__ void k_scatter_direct(const int* __restrict__ tr, const int* __restrict__ rt,
                                 int* __restrict__ cntE, int* __restrict__ cntR,
                                 int2* __restrict__ hrE, int2* __restrict__ tbR) {
    int i = blockIdx.x * 256 + threadIdx.x;
    if (i < NE) {
        int key = tr[i * 3 + 2];
        int pos = atomicAdd(&cntE[key], 1);
        if (pos < CAPE) hrE[(size_t)key * CAPE + pos] = make_int2(tr[i * 3 + 0], tr[i * 3 + 1]);
    } else if (i < NE + NER) {
        int e = i - NE;
        int key = rt[e * 3 + 0];
        int pos = atomicAdd(&cntR[key], 1);
        if (pos < CAPR) tbR[(size_t)key * CAPR + pos] = make_int2(rt[e * 3 + 1], rt[e * 3 + 2]);
    }
}

// ---------------------------------------------------------------- rel layer 0 + E16-l0 (merged)
// blocks 0..499: rel layer-0 body (epilogue writes AR2 = x @ Bp3l1^T + bias3)
// blocks 500..2999: E16-l0 rows 8*(b-500)..+7 = embh @ Wcomph^T + biasC (K=32)
__global__ __launch_bounds__(256) void k_rel0_e16(
    const float* __restrict__ AR,
    const float* __restrict__ vec,
    const float* __restrict__ abin,
    const int2* __restrict__ tbR,
    const int* __restrict__ cntR,
    const float* __restrict__ Bp3l1,
    const float* __restrict__ bias3,
    float* __restrict__ AR2,
    const _Float16* __restrict__ embh,
    const _Float16* __restrict__ Wcomph,
    const float* __restrict__ biasC,
    __half* __restrict__ E16)
{
    __shared__ float sS[4][64], sA[4][64];
    __shared__ float xrow[64];
    __shared__ float xs[8][33];
    if (blockIdx.x >= N_REL) {
        // ---- E16-l0 branch: pure compute, inputs finalized by k_pack_all
        int b2 = blockIdx.x - N_REL;          // 0..2499
        int t = threadIdx.x;
        int nn = t >> 5, d = t & 31;
        int n = b2 * 8 + nn;
        xs[nn][d] = (float)embh[(size_t)n * 32 + d];
        __syncthreads();
        const float* xr_ = xs[nn];
#pragma unroll
        for (int mm = 0; mm < 16; ++mm) {
            int m = (t & 31) + mm * 32;
            const __half2* wr2 = (const __half2*)(Wcomph + (size_t)m * 32);
            float a = biasC[m];
#pragma unroll
            for (int d2 = 0; d2 < 16; ++d2) {
                float2 wv = __half22float2(wr2[d2]);
                a = fmaf(xr_[2 * d2], wv.x, a);
                a = fmaf(xr_[2 * d2 + 1], wv.y, a);
            }
            E16[(size_t)n * 512 + m] = __float2half_rn(a);
        }
        return;
    }
    // ---- rel layer-0 body
    int n = blockIdx.x;
    int w = threadIdx.x >> 6, col = threadIdx.x & 63;
    int head = col >> 3;
    float ah = AR[n * 256 + col];
    float vc = vec[col];
    int dd = cntR[n]; if (dd > CAPR) dd = CAPR;
    int e0 = n * CAPR, e1 = e0 + dd;
    float s = 0.f, acc = 0.f;
    for (int i = e0 + w * 4; i < e1; i += 16) {
        int i0 = i;
        int i1 = (i + 1 < e1) ? i + 1 : e1 - 1;
        int i2 = (i + 2 < e1) ? i + 2 : e1 - 1;
        int i3 = (i + 3 < e1) ? i + 3 : e1 - 1;
        int2 t0 = tbR[i0], t1 = tbR[i1], t2 = tbR[i2], t3 = tbR[i3];
        float v0 = leaky(ah + AR[t0.x * 256 + 64 + col]) * vc;
        float v1 = leaky(ah + AR[t1.x * 256 + 64 + col]) * vc;
        float v2 = leaky(ah + AR[t2.x * 256 + 64 + col]) * vc;
        float v3 = leaky(ah + AR[t3.x * 256 + 64 + col]) * vc;
        float g0 = AR[t0.x * 256 + 128 + col];
        float g1 = AR[t1.x * 256 + 128 + col];
        float g2 = AR[t2.x * 256 + 128 + col];
        float g3 = AR[t3.x * 256 + 128 + col];
#pragma unroll
        for (int o = 1; o < 8; o <<= 1) {
            v0 += __shfl_xor(v0, o, 64); v1 += __shfl_xor(v1, o, 64);
            v2 += __shfl_xor(v2, o, 64); v3 += __shfl_xor(v3, o, 64);
        }
        float w0 = __expf(v0 + abin[t0.y * 8 + head]);
        float w1 = (i + 1 < e1) ? __expf(v1 + abin[t1.y * 8 + head]) : 0.f;
        float w2 = (i + 2 < e1) ? __expf(v2 + abin[t2.y * 8 + head]) : 0.f;
        float w3 = (i + 3 < e1) ? __expf(v3 + abin[t3.y * 8 + head]) : 0.f;
        s += (w0 + w1) + (w2 + w3);
        acc = fmaf(w0, g0, acc); acc = fmaf(w1, g1, acc);
        acc = fmaf(w2, g2, acc); acc = fmaf(w3, g3, acc);
    }
    sS[w][col] = s; sA[w][col] = acc;
    __syncthreads();
    if (w == 0) {
        s = (sS[0][col] + sS[1][col]) + (sS[2][col] + sS[3][col]);
        acc = (sA[0][col] + sA[1][col]) + (sA[2][col] + sA[3][col]);
        float upd = acc / (s + EPSF);
        xrow[col] = fmaxf(AR[n * 256 + 192 + col] + upd, 0.f);
    }
    __syncthreads();
    int t = threadIdx.x;
    float a = bias3[t];
    const float* br = Bp3l1 + (size_t)t * 64;
    float a0 = 0.f, a1 = 0.f;
#pragma unroll 8
    for (int k = 0; k < 64; k += 2) {
        a0 = fmaf(xrow[k], br[k], a0);
        a1 = fmaf(xrow[k + 1], br[k + 1], a1);
    }
    AR2[(size_t)n * 256 + t] = a + a0 + a1;
}

// ---------------------------------------------------------------- rel layer 1 (FINAL: R512 + out-proj)
__global__ __launch_bounds__(256) void k_rel_fused1(
    const float* __restrict__ AR,
    const float* __restrict__ vec,
    const float* __restrict__ abin,
    const int2* __restrict__ tbR,
    const int* __restrict__ cntR,
    const _Float16* __restrict__ Bp2f,
    __half* __restrict__ R512,
    const float* __restrict__ Wp2r,
    const float* __restrict__ b2r,
    float* __restrict__ outRel)
{
    __shared__ float sS[4][64], sA[4][64];
    __shared__ float xrow[64];
    int n = blockIdx.x;
    int w = threadIdx.x >> 6, col = threadIdx.x & 63;
    int head = col >> 3;
    float ah = AR[n * 256 + col];
    float vc = vec[col];
    int dd = cntR[n]; if (dd > CAPR) dd = CAPR;
    int e0 = n * CAPR, e1 = e0 + dd;
    float s = 0.f, acc = 0.f;
    for (int i = e0 + w * 4; i < e1; i += 16) {
        int i0 = i;
        int i1 = (i + 1 < e1) ? i + 1 : e1 - 1;
        int i2 = (i + 2 < e1) ? i + 2 : e1 - 1;
        int i3 = (i + 3 < e1) ? i + 3 : e1 - 1;
        int2 t0 = tbR[i0], t1 = tbR[i1], t2 = tbR[i2], t3 = tbR[i3];
        float v0 = leaky(ah + AR[t0.x * 256 + 64 + col]) * vc;
        float v1 = leaky(ah + AR[t1.x * 256 + 64 + col]) * vc;
        float v2 = leaky(ah + AR[t2.x * 256 + 64 + col]) * vc;
        float v3 = leaky(ah + AR[t3.x * 256 + 64 + col]) * vc;
        float g0 = AR[t0.x * 256 + 128 + col];
        float g1 = AR[t1.x * 256 + 128 + col];
        float g2 = AR[t2.x * 256 + 128 + col];
        float g3 = AR[t3.x * 256 + 128 + col];
#pragma unroll
        for (int o = 1; o < 8; o <<= 1) {
            v0 += __shfl_xor(v0, o, 64); v1 += __shfl_xor(v1, o, 64);
            v2 += __shfl_xor(v2, o, 64); v3 += __shfl_xor(v3, o, 64);
        }
        float w0 = __expf(v0 + abin[t0.y * 8 + head]);
        float w1 = (i + 1 < e1) ? __expf(v1 + abin[t1.y * 8 + head]) : 0.f;
        float w2 = (i + 2 < e1) ? __expf(v2 + abin[t2.y * 8 + head]) : 0.f;
        float w3 = (i + 3 < e1) ? __expf(v3 + abin[t3.y * 8 + head]) : 0.f;
        s += (w0 + w1) + (w2 + w3);
        acc = fmaf(w0, g0, acc); acc = fmaf(w1, g1, acc);
        acc = fmaf(w2, g2, acc); acc = fmaf(w3, g3, acc);
    }
    sS[w][col] = s; sA[w][col] = acc;
    __syncthreads();
    if (w == 0) {
        s = (sS[0][col] + sS[1][col]) + (sS[2][col] + sS[3][col]);
        acc = (sA[0][col] + sA[1][col]) + (sA[2][col] + sA[3][col]);
        float upd = acc / (s + EPSF);
        xrow[col] = fmaxf(AR[n * 256 + 192 + col] + upd, 0.f);
    }
    __syncthreads();
    int t = threadIdx.x;
#pragma unroll
    for (int mm = 0; mm < 2; ++mm) {
        int m = t + mm * 256;
        const _Float16* br = Bp2f + (size_t)m * 64;
        float a = 0.f;
#pragma unroll 8
        for (int k = 0; k < 64; ++k) a = fmaf(xrow[k], (float)br[k], a);
        R512[(size_t)n * 512 + m] = __float2half_rn(a);
    }
    if (t < 16) {
        float a = b2r[t];
        for (int k = 0; k < 64; ++k) a = fmaf(xrow[k], Wp2r[t * 64 + k], a);
        outRel[n * 16 + t] = a;
    }
}

// ---------------------------------------------------------------- ent layer
template<int FINAL>
__global__ __launch_bounds__(256) void k_ent_fused(
    const __half* __restrict__ E16,
    const __half* __restrict__ Fl,
    const _Float16* __restrict__ vech,
    const int2* __restrict__ hrE,
    const int* __restrict__ cntE,
    __half* __restrict__ xout,
    const float* __restrict__ W2Tf,
    const float* __restrict__ b2,
    float* __restrict__ outp)
{
    int wave = (blockIdx.x * 256 + threadIdx.x) >> 6;
    int lane = threadIdx.x & 63;
    int half = lane >> 5, sl = lane & 31;
    int n = wave * 2 + half;
    const _Float16* Eb = (const _Float16*)E16;
    const _Float16* Fb = (const _Float16*)Fl;
    const _Float16* Erow = Eb + (size_t)n * 512;

    f16x4 pt = *(const f16x4*)(Erow + 4 * sl);
    f16x4 vc = *(const f16x4*)(vech + 4 * sl);
    f16x8 se = *(const f16x8*)(Erow + 128 + 8 * sl);

    int dd = cntE[n]; if (dd > CAPE) dd = CAPE;
    int e0 = n * CAPE, e1 = e0 + dd;
    float s = 0.f;
    float acc0 = 0.f, acc1 = 0.f, acc2 = 0.f, acc3 = 0.f;
    f16x8 sfa = {0, 0, 0, 0, 0, 0, 0, 0};
    f16x8 sfb = {0, 0, 0, 0, 0, 0, 0, 0};
    const f16x8* Ex = (const f16x8*)(Eb + 128) + sl;
    const f16x8* Fx = (const f16x8*)Fb + sl;
    for (int i = e0; i < e1; i += 4) {
        bool h1 = (i + 1 < e1), h2 = (i + 2 < e1), h3 = (i + 3 < e1);
        int j1 = h1 ? i + 1 : e1 - 1;
        int j2 = h2 ? i + 2 : e1 - 1;
        int j3 = h3 ? i + 3 : e1 - 1;
        int2 ev0 = hrE[i], ev1 = hrE[j1], ev2 = hrE[j2], ev3 = hrE[j3];
        f16x8 A0 = Ex[(size_t)ev0.x * 64];
        f16x8 F0 = Fx[(size_t)ev0.y * 64];
        f16x8 A1 = Ex[(size_t)ev1.x * 64];
        f16x8 F1 = Fx[(size_t)ev1.y * 64];
        f16x8 A2 = Ex[(size_t)ev2.x * 64];
        f16x8 F2 = Fx[(size_t)ev2.y * 64];
        f16x8 A3 = Ex[(size_t)ev3.x * 64];
        f16x8 F3 = Fx[(size_t)ev3.y * 64];
        f16x8 t0 = A0 + F0;
        f16x8 t1 = A1 + F1;
        f16x8 t2 = A2 + F2;
        f16x8 t3 = A3 + F3;
        sfa = sfa + F0;
        if (h1) sfb = sfb + F1;
        if (h2) sfa = sfa + F2;
        if (h3) sfb = sfb + F3;
        f16x4 z0 = __builtin_shufflevector(t0, t0, 0, 1, 2, 3) + pt;
        f16x4 z1 = __builtin_shufflevector(t1, t1, 0, 1, 2, 3) + pt;
        f16x4 z2 = __builtin_shufflevector(t2, t2, 0, 1, 2, 3) + pt;
        f16x4 z3 = __builtin_shufflevector(t3, t3, 0, 1, 2, 3) + pt;
        z0 = __builtin_elementwise_max(z0, z0 * (_Float16)0.2f);
        z1 = __builtin_elementwise_max(z1, z1 * (_Float16)0.2f);
        z2 = __builtin_elementwise_max(z2, z2 * (_Float16)0.2f);
        z3 = __builtin_elementwise_max(z3, z3 * (_Float16)0.2f);
        z0 = z0 * vc; z1 = z1 * vc; z2 = z2 * vc; z3 = z3 * vc;
        float v0 = ((float)z0[0] + (float)z0[1]) + ((float)z0[2] + (float)z0[3]);
        float v1 = ((float)z1[0] + (float)z1[1]) + ((float)z1[2] + (float)z1[3]);
        float v2 = ((float)z2[0] + (float)z2[1]) + ((float)z2[2] + (float)z2[3]);
        float v3 = ((float)z3[0] + (float)z3[1]) + ((float)z3[2] + (float)z3[3]);
        v0 += __shfl_xor(v0, 1, 64); v1 += __shfl_xor(v1, 1, 64);
        v2 += __shfl_xor(v2, 1, 64); v3 += __shfl_xor(v3, 1, 64);
        v0 += __shfl_xor(v0, 2, 64); v1 += __shfl_xor(v1, 2, 64);
        v2 += __shfl_xor(v2, 2, 64); v3 += __shfl_xor(v3, 2, 64);
        float w0 = __expf(v0);
        float w1 = h1 ? __expf(v1) : 0.f;
        float w2 = h2 ? __expf(v2) : 0.f;
        float w3 = h3 ? __expf(v3) : 0.f;
        s += (w0 + w1) + (w2 + w3);
        acc0 = fmaf(w0, (float)t0[4], acc0); acc0 = fmaf(w1, (float)t1[4], acc0);
        acc0 = fmaf(w2, (float)t2[4], acc0); acc0 = fmaf(w3, (float)t3[4], acc0);
        acc1 = fmaf(w0, (float)t0[5], acc1); acc1 = fmaf(w1, (float)t1[5], acc1);
        acc1 = fmaf(w2, (float)t2[5], acc1); acc1 = fmaf(w3, (float)t3[5], acc1);
        acc2 = fmaf(w0, (float)t0[6], acc2); acc2 = fmaf(w1, (float)t1[6], acc2);
        acc2 = fmaf(w2, (float)t2[6], acc2); acc2 = fmaf(w3, (float)t3[6], acc2);
        acc3 = fmaf(w0, (float)t0[7], acc3); acc3 = fmaf(w1, (float)t1[7], acc3);
        acc3 = fmaf(w2, (float)t2[7], acc3); acc3 = fmaf(w3, (float)t3[7], acc3);
    }

    float invd = 1.f / ((float)dd + EPSF);
    f16x8 sf = sfa + sfb;
    float z0 = leaky((float)pt[0] + (float)se[0] + (float)sf[0] * invd) * (float)vc[0];
    float z1 = leaky((float)pt[1] + (float)se[1] + (float)sf[1] * invd) * (float)vc[1];
    float z2 = leaky((float)pt[2] + (float)se[2] + (float)sf[2] * invd) * (float)vc[2];
    float z3 = leaky((float)pt[3] + (float)se[3] + (float)sf[3] * invd) * (float)vc[3];
    float vs = (z0 + z1) + (z2 + z3);
    vs += __shfl_xor(vs, 1, 64);
    vs += __shfl_xor(vs, 2, 64);
    float ws = __expf(vs);
    s += ws;
    acc0 = fmaf(ws, (float)se[4] + (float)sf[4] * invd, acc0);
    acc1 = fmaf(ws, (float)se[5] + (float)sf[5] * invd, acc1);
    acc2 = fmaf(ws, (float)se[6] + (float)sf[6] * invd, acc2);
    acc3 = fmaf(ws, (float)se[7] + (float)sf[7] * invd, acc3);

    float inv = 1.f / (s + EPSF);
    f16x4 res = *(const f16x4*)(Erow + 384 + 4 * sl);
    float o0 = fmaxf((float)res[0] + acc0 * inv, 0.f);
    float o1 = fmaxf((float)res[1] + acc1 * inv, 0.f);
    float o2 = fmaxf((float)res[2] + acc2 * inv, 0.f);
    float o3 = fmaxf((float)res[3] + acc3 * inv, 0.f);
    if (!FINAL) {
        f16x4 o = { (_Float16)o0, (_Float16)o1, (_Float16)o2, (_Float16)o3 };
        *(f16x4*)((_Float16*)xout + (size_t)n * 128 + 4 * sl) = o;
    } else {
        __shared__ float xs[8][132];
        int nib = threadIdx.x >> 5;
        *(float4*)&xs[nib][4 * sl] = make_float4(o0, o1, o2, o3);
        __syncthreads();
        int nn = threadIdx.x >> 5, j = threadIdx.x & 31;
        float a = b2[j];
        const float* xr_ = xs[nn];
#pragma unroll 8
        for (int k = 0; k < 128; k += 4) {
            float4 xv = *(const float4*)&xr_[k];
            a = fmaf(xv.x, W2Tf[(k + 0) * 32 + j], a);
            a = fmaf(xv.y, W2Tf[(k + 1) * 32 + j], a);
            a = fmaf(xv.z, W2Tf[(k + 2) * 32 + j], a);
            a = fmaf(xv.w, W2Tf[(k + 3) * 32 + j], a);
        }
        outp[(size_t)(blockIdx.x * 8 + nn) * 32 + j] = a;
    }
}

// ---------------------------------------------------------------- launch
extern "C" void kernel_launch(void* const* d_in, const int* in_sizes, int n_in,
                              void* d_out, int out_size, void* d_ws, size_t ws_size,
                              hipStream_t stream) {
    const float* emb_ent      = (const float*)d_in[0];
    const float* emb_rel      = (const float*)d_in[1];
    const int*   tr           = (const int*)d_in[2];
    const int*   rt           = (const int*)d_in[3];
    const float* ent_proj1_W  = (const float*)d_in[4];
    const float* ent_proj1_b  = (const float*)d_in[5];
    const float* rel_proj1_W  = (const float*)d_in[6];
    const float* rel_proj1_b  = (const float*)d_in[7];
    const float* rel_attn_W   = (const float*)d_in[8];
    const float* rel_attn_b   = (const float*)d_in[9];
    const float* rel_attn_bin = (const float*)d_in[10];
    const float* rel_attn_vec = (const float*)d_in[11];
    const float* rel_aggr_W   = (const float*)d_in[12];
    const float* rel_aggr_b   = (const float*)d_in[13];
    const float* res_rel_W    = (const float*)d_in[14];
    const float* res_rel_b    = (const float*)d_in[15];
    const float* ent_attn_W   = (const float*)d_in[16];
    const float* ent_attn_b   = (const float*)d_in[17];
    const float* ent_attn_vec = (const float*)d_in[18];
    const float* ent_aggr_W   = (const float*)d_in[19];
    const float* ent_aggr_b   = (const float*)d_in[20];
    const float* res_ent_W    = (const float*)d_in[21];
    const float* res_ent_b    = (const float*)d_in[22];
    const float* ent_proj2_W  = (const float*)d_in[23];
    const float* ent_proj2_b  = (const float*)d_in[24];
    const float* rel_proj2_W  = (const float*)d_in[25];
    const float* rel_proj2_b  = (const float*)d_in[26];
    float* out = (float*)d_out;

    size_t off = 0;
    char* base = (char*)d_ws;
    auto alloc = [&](size_t nbytes) -> void* {
        void* p = base + off;
        off += (nbytes + 255) & ~(size_t)255;
        return p;
    };
    _Float16* embh   = (_Float16*)alloc((size_t)MPE * 32 * 2);
    __half*   xeb    = (__half*)alloc((size_t)MPE * 128 * 2);
    __half*   E16    = (__half*)alloc((size_t)MPE * 512 * 2);
    __half*   R512   = (__half*)alloc((size_t)512 * 512 * 2);
    float*    AR     = (float*)alloc((size_t)N_REL * 256 * 4);
    float*    AR2    = (float*)alloc((size_t)N_REL * 256 * 4);
    _Float16* Bp1f   = (_Float16*)alloc((size_t)512 * 128 * 2);
    float*    bias1  = (float*)alloc(512 * 4);
    _Float16* Bp2f   = (_Float16*)alloc(512 * 64 * 2);
    float*    Bp3    = (float*)alloc((size_t)256 * 64 * 4);
    float*    bias3  = (float*)alloc(256 * 4);
    _Float16* Wcomph = (_Float16*)alloc(512 * 32 * 2);
    float*    biasC  = (float*)alloc(512 * 4);
    float*    W2Tf   = (float*)alloc(128 * 32 * 4);
    _Float16* vech   = (_Float16*)alloc(2 * 128 * 2);
    int*  cnt   = (int*)alloc((size_t)(N_ENT + N_REL) * 4);
    int*  cntE  = cnt;
    int*  cntR  = cnt + N_ENT;
    int2* hrE   = (int2*)alloc((size_t)N_ENT * CAPE * 8);
    int2* tbR   = (int2*)alloc((size_t)N_REL * CAPR * 8);

    // 1. pack + compose + direct AR (LDS-hoisted) + zero counters
    k_pack_all<<<640, 256, 0, stream>>>(
        emb_ent, emb_rel,
        ent_attn_W, ent_attn_b, ent_aggr_W, ent_aggr_b, res_ent_W, res_ent_b,
        rel_attn_W, rel_attn_b, rel_aggr_W, rel_aggr_b, res_rel_W, res_rel_b,
        ent_proj1_W, ent_proj1_b, rel_proj1_W, rel_proj1_b,
        ent_proj2_W, ent_attn_vec,
        embh, Bp1f, bias1, Bp2f, Bp3, bias3,
        Wcomph, biasC, AR, W2Tf, vech, cnt);

    // 2. direct bucket scatter (count + scatter fused, no scan)
    k_scatter_direct<<<(NE + NER + 255) / 256, 256, 0, stream>>>(
        tr, rt, cntE, cntR, hrE, tbR);

    // 3. rel layer 0 (epilogue AR2) + E16-l0 compute (extra blocks)
    k_rel0_e16<<<N_REL + 2500, 256, 0, stream>>>(
        AR, rel_attn_vec, rel_attn_bin, tbR, cntR,
        Bp3, bias3, AR2,
        embh, Wcomph, biasC, E16);

    // 4. rel layer 1 (FINAL: R512 + rel output projection)
    k_rel_fused1<<<N_REL, 256, 0, stream>>>(
        AR2, rel_attn_vec + 64, rel_attn_bin + 80, tbR, cntR,
        Bp2f, R512, rel_proj2_W, rel_proj2_b, out + (size_t)N_ENT * 32);

    // 5. ent layer 0
    k_ent_fused<0><<<(N_ENT / 2 * 64) / 256, 256, 0, stream>>>(
        E16, R512, vech, hrE, cntE, xeb, nullptr, nullptr, nullptr);

    // 6. ent layer 1 input GEMM (K=128)
    k_hgemm<<<dim3(8, 157), 256, 0, stream>>>(
        (const _Float16*)xeb, Bp1f, bias1, E16, nullptr, N_ENT, 512, 128, 512);

    // 7. ent layer 1 (FINAL: fused ent output projection)
    k_ent_fused<1><<<(N_ENT / 2 * 64) / 256, 256, 0, stream>>>(
        E16, R512 + 256, vech + 128, hrE, cntE, nullptr,
        W2Tf, ent_proj2_b, out);
}

// Round 16
// 192.148 us; speedup vs baseline: 1.1422x; 1.1422x over previous
//
#include <hip/hip_runtime.h>
#include <hip/hip_fp16.h>
#include <math.h>

constexpr int N_ENT = 20000;
constexpr int N_REL = 500;
constexpr int NE    = 300000;   // entity triplets
constexpr int NER   = 50000;    // relation triplets
constexpr int MPE   = 20096;    // 157*128 (padded entity rows)
constexpr int CAPE  = 64;       // per-entity edge bucket capacity (Poisson(15))
constexpr int CAPR  = 192;      // per-relation edge bucket capacity (Poisson(100))
constexpr float EPSF = 1e-16f;

__device__ __forceinline__ float leaky(float x) { return x > 0.f ? x : 0.2f * x; }

typedef __attribute__((ext_vector_type(8))) _Float16 f16x8;
typedef __attribute__((ext_vector_type(4))) _Float16 f16x4;
typedef __attribute__((ext_vector_type(4))) float f32x4;

__device__ __forceinline__ float bp1val(const float* Wa, const float* Wg,
                                        const float* Wr, int row, int k) {
    if (row < 128) return Wa[row * 320 + k];
    if (row < 384) {
        int m = row - 128;
        int c = 4 * (m >> 3) + (m & 3);
        return ((m & 4) == 0) ? Wa[c * 320 + 128 + k] : Wg[c * 192 + k];
    }
    return Wr[(row - 384) * 128 + k];
}
__device__ __forceinline__ float bp3val(const float* Wa, const float* Wg,
                                        const float* Wr, int row, int k) {
    if (row < 64) return Wa[row * 128 + k];
    if (row < 128) return Wa[(row - 64) * 128 + 64 + k];
    if (row < 192) return Wg[(row - 128) * 64 + k];
    return Wr[(row - 192) * 64 + k];
}

// ---------------------------------------------------------------- MFMA fp16 GEMM
__global__ __launch_bounds__(256) void k_hgemm(
    const _Float16* __restrict__ A,
    const _Float16* __restrict__ B,
    const float* __restrict__ bias,
    __half* __restrict__ O16, float* __restrict__ O32,
    int M, int N, int K, int ldo)
{
    __shared__ __align__(16) _Float16 lA[4 * 128 * 8];
    __shared__ __align__(16) _Float16 lB[4 * 64 * 8];
    int tid = threadIdx.x;
    int m0 = blockIdx.y * 128, n0 = blockIdx.x * 64;
    int l = tid & 63, w = tid >> 6;
    int wr = w >> 1, wc = w & 1;
    int kq = l >> 4, lr = l & 15;

    int sA0 = tid, sA1 = tid + 256;
    const uint4* pA0 = (const uint4*)(A + (size_t)(m0 + (sA0 & 127)) * K) + (sA0 >> 7);
    const uint4* pA1 = (const uint4*)(A + (size_t)(m0 + (sA1 & 127)) * K) + (sA1 >> 7);
    const uint4* pB  = (const uint4*)(B + (size_t)(n0 + (tid & 63)) * K) + (tid >> 6);

    f32x4 acc[4][2] = {};
    int nk = K >> 5;
    uint4 va0 = pA0[0], va1 = pA1[0], vb = pB[0];
    for (int t = 0; t < nk; ++t) {
        ((uint4*)lA)[sA0] = va0;
        ((uint4*)lA)[sA1] = va1;
        ((uint4*)lB)[tid] = vb;
        __syncthreads();
        if (t + 1 < nk) {
            va0 = pA0[(t + 1) * 4];
            va1 = pA1[(t + 1) * 4];
            vb  = pB[(t + 1) * 4];
        }
        f16x8 bf0 = *(const f16x8*)&lB[(kq * 64 + wc * 32 + lr) * 8];
        f16x8 bf1 = *(const f16x8*)&lB[(kq * 64 + wc * 32 + 16 + lr) * 8];
#pragma unroll
        for (int fm = 0; fm < 4; ++fm) {
            f16x8 af = *(const f16x8*)&lA[(kq * 128 + wr * 64 + fm * 16 + lr) * 8];
            acc[fm][0] = __builtin_amdgcn_mfma_f32_16x16x32_f16(af, bf0, acc[fm][0], 0, 0, 0);
            acc[fm][1] = __builtin_amdgcn_mfma_f32_16x16x32_f16(af, bf1, acc[fm][1], 0, 0, 0);
        }
        __syncthreads();
    }
    int gn0 = n0 + wc * 32 + lr;
    int gn1 = gn0 + 16;
    float bc0 = (bias && gn0 < N) ? bias[gn0] : 0.f;
    float bc1 = (bias && gn1 < N) ? bias[gn1] : 0.f;
#pragma unroll
    for (int fm = 0; fm < 4; ++fm) {
#pragma unroll
        for (int j = 0; j < 4; ++j) {
            int gm = m0 + wr * 64 + fm * 16 + kq * 4 + j;
            if (gm >= M) continue;
            float v0 = acc[fm][0][j] + bc0;
            float v1 = acc[fm][1][j] + bc1;
            if (O16) {
                if (gn0 < N) O16[(size_t)gm * ldo + gn0] = __float2half_rn(v0);
                if (gn1 < N) O16[(size_t)gm * ldo + gn1] = __float2half_rn(v1);
            } else {
                if (gn0 < N) O32[(size_t)gm * ldo + gn0] = v0;
                if (gn1 < N) O32[(size_t)gm * ldo + gn1] = v1;
            }
        }
    }
}

// ---------------------------------------------------------------- mega-pack (grid: 640 blocks x 256)
__global__ void k_pack_all(
    const float* __restrict__ emb_ent, const float* __restrict__ emb_rel,
    const float* __restrict__ Wa_e, const float* __restrict__ ba_e,
    const float* __restrict__ Wg_e, const float* __restrict__ bg_e,
    const float* __restrict__ Wres_e, const float* __restrict__ bres_e,
    const float* __restrict__ Wa_r, const float* __restrict__ ba_r,
    const float* __restrict__ Wg_r, const float* __restrict__ bg_r,
    const float* __restrict__ Wres_r, const float* __restrict__ bres_r,
    const float* __restrict__ Wp1e, const float* __restrict__ p1b,
    const float* __restrict__ Wp1r, const float* __restrict__ p1rb,
    const float* __restrict__ Wp2e, const float* __restrict__ vec_e,
    _Float16* __restrict__ embh,
    _Float16* __restrict__ Bp1f, float* __restrict__ bias1,
    _Float16* __restrict__ Bp2f,
    float* __restrict__ Bp3, float* __restrict__ bias3,
    _Float16* __restrict__ Wcomph, float* __restrict__ biasC,
    float* __restrict__ AR,
    float* __restrict__ W2Tf,
    _Float16* __restrict__ vech,
    int* __restrict__ cnt)
{
    __shared__ float xsh[64];
    int gid = blockIdx.x * 256 + threadIdx.x;
    bool arblk = (blockIdx.x < N_REL);  // blocks 0..499 own AR row n = blockIdx.x
    if (arblk && threadIdx.x < 64) {    // hoisted intermediate x[d], shared per block
        int d = threadIdx.x;
        int n = blockIdx.x;
        float x = p1rb[d];
        for (int k = 0; k < 16; ++k)
            x = fmaf(emb_rel[n * 16 + k], Wp1r[d * 16 + k], x);
        xsh[d] = x;
    }
    __syncthreads();                    // uniform per block (all-in or all-out)
    if (arblk) {
        int n = blockIdx.x, j = threadIdx.x;
        float bb;
        if (j < 64) bb = ba_r[j];
        else if (j < 128) bb = 0.f;
        else if (j < 192) bb = bg_r[j - 128];
        else bb = bres_r[j - 192];
        float a0 = 0.f, a1 = 0.f;
        for (int d = 0; d < 64; d += 2) {
            a0 = fmaf(bp3val(Wa_r, Wg_r, Wres_r, j, d), xsh[d], a0);
            a1 = fmaf(bp3val(Wa_r, Wg_r, Wres_r, j, d + 1), xsh[d + 1], a1);
        }
        AR[n * 256 + j] = bb + a0 + a1;
    }
    if (gid * 4 < N_ENT * 32) {         // embh, 4-wide
        float4 e = *(const float4*)&emb_ent[gid * 4];
        f16x4 h = { (_Float16)e.x, (_Float16)e.y, (_Float16)e.z, (_Float16)e.w };
        *(f16x4*)&embh[gid * 4] = h;
    }
    const float* Wa1 = Wa_e + 128 * 320;
    const float* Wg1 = Wg_e + 128 * 192;
    const float* Wr1 = Wres_e + 128 * 128;
    if (gid < 512 * 128) {          // Bp1f l=1
        int row = gid >> 7, k = gid & 127;
        Bp1f[gid] = (_Float16)bp1val(Wa1, Wg1, Wr1, row, k);
    }
    if (gid < 512 * 64) {           // Bp2f[l*256 + m][64]
        int row = gid >> 6, k = gid & 63;
        int l = row >> 8, m = row & 255;
        int c = 4 * (m >> 3) + (m & 3);
        const float* Wa = Wa_e + (size_t)l * 128 * 320;
        const float* Wg = Wg_e + (size_t)l * 128 * 192;
        float v = ((m & 4) == 0) ? Wa[c * 320 + 256 + k] : Wg[c * 192 + 128 + k];
        Bp2f[gid] = (_Float16)v;
    }
    const float* Wa1r = Wa_r + 64 * 128;
    const float* Wg1r = Wg_r + 64 * 64;
    const float* Wr1r = Wres_r + 64 * 64;
    if (gid < 256 * 64) {           // Bp3 l=1
        int row = gid >> 6, k = gid & 63;
        Bp3[gid] = bp3val(Wa1r, Wg1r, Wr1r, row, k);
    }
    if (gid < 512 * 32) {           // Wcomp ent l0 = Bp1_l0 @ P1e
        int n = gid >> 5, j = gid & 31;
        float a = 0.f;
        for (int d = 0; d < 128; ++d)
            a += bp1val(Wa_e, Wg_e, Wres_e, n, d) * Wp1e[d * 32 + j];
        Wcomph[gid] = (_Float16)a;
    }
    if (gid < 512) {                // bias1 (l=1) and biasC (l=0 composed)
        int j = gid;
        float v;
        if (j < 128) v = ba_e[128 + j];
        else if (j < 384) {
            int m = j - 128, c = 4 * (m >> 3) + (m & 3);
            v = ((m & 4) == 0) ? 0.f : bg_e[128 + c];
        } else v = bres_e[128 + j - 384];
        bias1[j] = v;
        float v0;
        if (j < 128) v0 = ba_e[j];
        else if (j < 384) {
            int m = j - 128, c = 4 * (m >> 3) + (m & 3);
            v0 = ((m & 4) == 0) ? 0.f : bg_e[c];
        } else v0 = bres_e[j - 384];
        float a = v0;
        for (int d = 0; d < 128; ++d)
            a += bp1val(Wa_e, Wg_e, Wres_e, j, d) * p1b[d];
        biasC[j] = a;
    }
    if (gid < 256) {                // bias3 (rel l=1)
        int j = gid;
        float v;
        if (j < 64) v = ba_r[64 + j];
        else if (j < 128) v = 0.f;
        else if (j < 192) v = bg_r[64 + (j - 128)];
        else v = bres_r[64 + (j - 192)];
        bias3[j] = v;
    }
    if (gid < 128 * 32) {           // W2Tf[k][j] = ent_proj2_W[j][k]
        int k = gid >> 5, j = gid & 31;
        W2Tf[gid] = Wp2e[j * 128 + k];
    }
    if (gid < 2 * 128) vech[gid] = (_Float16)vec_e[gid];
    if (gid < N_ENT + N_REL) cnt[gid] = 0;
}

// ---------------------------------------------------------------- direct bucket scatter
__global__ void k_scatter_direct(const int* __restrict__ tr, const int* __restrict__ rt,
                                 int* __restrict__ cntE, int* __restrict__ cntR,
                                 int2* __restrict__ hrE, int2* __restrict__ tbR) {
    int i = blockIdx.x * 256 + threadIdx.x;
    if (i < NE) {
        int key = tr[i * 3 + 2];
        int pos = atomicAdd(&cntE[key], 1);
        if (pos < CAPE) hrE[(size_t)key * CAPE + pos] = make_int2(tr[i * 3 + 0], tr[i * 3 + 1]);
    } else if (i < NE + NER) {
        int e = i - NE;
        int key = rt[e * 3 + 0];
        int pos = atomicAdd(&cntR[key], 1);
        if (pos < CAPR) tbR[(size_t)key * CAPR + pos] = make_int2(rt[e * 3 + 1], rt[e * 3 + 2]);
    }
}

// ---------------------------------------------------------------- rel layer
template<int FINAL>
__global__ __launch_bounds__(256) void k_rel_fused(
    const float* __restrict__ AR,
    const float* __restrict__ vec,
    const float* __restrict__ abin,
    const int2* __restrict__ tbR,
    const int* __restrict__ cntR,
    const float* __restrict__ Bp3l1,
    const float* __restrict__ bias3,
    float* __restrict__ AR2,
    const _Float16* __restrict__ Bp2f,
    __half* __restrict__ R512,
    const float* __restrict__ Wp2r,
    const float* __restrict__ b2r,
    float* __restrict__ outRel)
{
    __shared__ float sS[4][64], sA[4][64];
    __shared__ float xrow[64];
    int n = blockIdx.x;
    int w = threadIdx.x >> 6, col = threadIdx.x & 63;
    int head = col >> 3;
    float ah = AR[n * 256 + col];
    float vc = vec[col];
    int dd = cntR[n]; if (dd > CAPR) dd = CAPR;
    int e0 = n * CAPR, e1 = e0 + dd;
    float s = 0.f, acc = 0.f;
    for (int i = e0 + w * 4; i < e1; i += 16) {
        int i0 = i;
        int i1 = (i + 1 < e1) ? i + 1 : e1 - 1;
        int i2 = (i + 2 < e1) ? i + 2 : e1 - 1;
        int i3 = (i + 3 < e1) ? i + 3 : e1 - 1;
        int2 t0 = tbR[i0], t1 = tbR[i1], t2 = tbR[i2], t3 = tbR[i3];
        float v0 = leaky(ah + AR[t0.x * 256 + 64 + col]) * vc;
        float v1 = leaky(ah + AR[t1.x * 256 + 64 + col]) * vc;
        float v2 = leaky(ah + AR[t2.x * 256 + 64 + col]) * vc;
        float v3 = leaky(ah + AR[t3.x * 256 + 64 + col]) * vc;
        float g0 = AR[t0.x * 256 + 128 + col];
        float g1 = AR[t1.x * 256 + 128 + col];
        float g2 = AR[t2.x * 256 + 128 + col];
        float g3 = AR[t3.x * 256 + 128 + col];
#pragma unroll
        for (int o = 1; o < 8; o <<= 1) {
            v0 += __shfl_xor(v0, o, 64); v1 += __shfl_xor(v1, o, 64);
            v2 += __shfl_xor(v2, o, 64); v3 += __shfl_xor(v3, o, 64);
        }
        float w0 = __expf(v0 + abin[t0.y * 8 + head]);
        float w1 = (i + 1 < e1) ? __expf(v1 + abin[t1.y * 8 + head]) : 0.f;
        float w2 = (i + 2 < e1) ? __expf(v2 + abin[t2.y * 8 + head]) : 0.f;
        float w3 = (i + 3 < e1) ? __expf(v3 + abin[t3.y * 8 + head]) : 0.f;
        s += (w0 + w1) + (w2 + w3);
        acc = fmaf(w0, g0, acc); acc = fmaf(w1, g1, acc);
        acc = fmaf(w2, g2, acc); acc = fmaf(w3, g3, acc);
    }
    sS[w][col] = s; sA[w][col] = acc;
    __syncthreads();
    if (w == 0) {
        s = (sS[0][col] + sS[1][col]) + (sS[2][col] + sS[3][col]);
        acc = (sA[0][col] + sA[1][col]) + (sA[2][col] + sA[3][col]);
        float upd = acc / (s + EPSF);
        xrow[col] = fmaxf(AR[n * 256 + 192 + col] + upd, 0.f);
    }
    __syncthreads();
    int t = threadIdx.x;
    if (!FINAL) {
        float a = bias3[t];
        const float* br = Bp3l1 + (size_t)t * 64;
        float a0 = 0.f, a1 = 0.f;
#pragma unroll 8
        for (int k = 0; k < 64; k += 2) {
            a0 = fmaf(xrow[k], br[k], a0);
            a1 = fmaf(xrow[k + 1], br[k + 1], a1);
        }
        AR2[(size_t)n * 256 + t] = a + a0 + a1;
    } else {
#pragma unroll
        for (int mm = 0; mm < 2; ++mm) {
            int m = t + mm * 256;
            const _Float16* br = Bp2f + (size_t)m * 64;
            float a = 0.f;
#pragma unroll 8
            for (int k = 0; k < 64; ++k) a = fmaf(xrow[k], (float)br[k], a);
            R512[(size_t)n * 512 + m] = __float2half_rn(a);
        }
        if (t < 16) {
            float a = b2r[t];
            for (int k = 0; k < 64; ++k) a = fmaf(xrow[k], Wp2r[t * 64 + k], a);
            outRel[n * 16 + t] = a;
        }
    }
}

// ---------------------------------------------------------------- ent layer
template<int FINAL>
__global__ __launch_bounds__(256) void k_ent_fused(
    const __half* __restrict__ E16,
    const __half* __restrict__ Fl,
    const _Float16* __restrict__ vech,
    const int2* __restrict__ hrE,
    const int* __restrict__ cntE,
    __half* __restrict__ xout,
    const float* __restrict__ W2Tf,
    const float* __restrict__ b2,
    float* __restrict__ outp)
{
    int wave = (blockIdx.x * 256 + threadIdx.x) >> 6;
    int lane = threadIdx.x & 63;
    int half = lane >> 5, sl = lane & 31;
    int n = wave * 2 + half;
    const _Float16* Eb = (const _Float16*)E16;
    const _Float16* Fb = (const _Float16*)Fl;
    const _Float16* Erow = Eb + (size_t)n * 512;

    f16x4 pt = *(const f16x4*)(Erow + 4 * sl);
    f16x4 vc = *(const f16x4*)(vech + 4 * sl);
    f16x8 se = *(const f16x8*)(Erow + 128 + 8 * sl);

    int dd = cntE[n]; if (dd > CAPE) dd = CAPE;
    int e0 = n * CAPE, e1 = e0 + dd;
    float s = 0.f;
    float acc0 = 0.f, acc1 = 0.f, acc2 = 0.f, acc3 = 0.f;
    f16x8 sfa = {0, 0, 0, 0, 0, 0, 0, 0};
    f16x8 sfb = {0, 0, 0, 0, 0, 0, 0, 0};
    const f16x8* Ex = (const f16x8*)(Eb + 128) + sl;
    const f16x8* Fx = (const f16x8*)Fb + sl;
    for (int i = e0; i < e1; i += 4) {
        bool h1 = (i + 1 < e1), h2 = (i + 2 < e1), h3 = (i + 3 < e1);
        int j1 = h1 ? i + 1 : e1 - 1;
        int j2 = h2 ? i + 2 : e1 - 1;
        int j3 = h3 ? i + 3 : e1 - 1;
        int2 ev0 = hrE[i], ev1 = hrE[j1], ev2 = hrE[j2], ev3 = hrE[j3];
        f16x8 A0 = Ex[(size_t)ev0.x * 64];
        f16x8 F0 = Fx[(size_t)ev0.y * 64];
        f16x8 A1 = Ex[(size_t)ev1.x * 64];
        f16x8 F1 = Fx[(size_t)ev1.y * 64];
        f16x8 A2 = Ex[(size_t)ev2.x * 64];
        f16x8 F2 = Fx[(size_t)ev2.y * 64];
        f16x8 A3 = Ex[(size_t)ev3.x * 64];
        f16x8 F3 = Fx[(size_t)ev3.y * 64];
        f16x8 t0 = A0 + F0;
        f16x8 t1 = A1 + F1;
        f16x8 t2 = A2 + F2;
        f16x8 t3 = A3 + F3;
        sfa = sfa + F0;
        if (h1) sfb = sfb + F1;
        if (h2) sfa = sfa + F2;
        if (h3) sfb = sfb + F3;
        f16x4 z0 = __builtin_shufflevector(t0, t0, 0, 1, 2, 3) + pt;
        f16x4 z1 = __builtin_shufflevector(t1, t1, 0, 1, 2, 3) + pt;
        f16x4 z2 = __builtin_shufflevector(t2, t2, 0, 1, 2, 3) + pt;
        f16x4 z3 = __builtin_shufflevector(t3, t3, 0, 1, 2, 3) + pt;
        z0 = __builtin_elementwise_max(z0, z0 * (_Float16)0.2f);
        z1 = __builtin_elementwise_max(z1, z1 * (_Float16)0.2f);
        z2 = __builtin_elementwise_max(z2, z2 * (_Float16)0.2f);
        z3 = __builtin_elementwise_max(z3, z3 * (_Float16)0.2f);
        z0 = z0 * vc; z1 = z1 * vc; z2 = z2 * vc; z3 = z3 * vc;
        float v0 = ((float)z0[0] + (float)z0[1]) + ((float)z0[2] + (float)z0[3]);
        float v1 = ((float)z1[0] + (float)z1[1]) + ((float)z1[2] + (float)z1[3]);
        float v2 = ((float)z2[0] + (float)z2[1]) + ((float)z2[2] + (float)z2[3]);
        float v3 = ((float)z3[0] + (float)z3[1]) + ((float)z3[2] + (float)z3[3]);
        v0 += __shfl_xor(v0, 1, 64); v1 += __shfl_xor(v1, 1, 64);
        v2 += __shfl_xor(v2, 1, 64); v3 += __shfl_xor(v3, 1, 64);
        v0 += __shfl_xor(v0, 2, 64); v1 += __shfl_xor(v1, 2, 64);
        v2 += __shfl_xor(v2, 2, 64); v3 += __shfl_xor(v3, 2, 64);
        float w0 = __expf(v0);
        float w1 = h1 ? __expf(v1) : 0.f;
        float w2 = h2 ? __expf(v2) : 0.f;
        float w3 = h3 ? __expf(v3) : 0.f;
        s += (w0 + w1) + (w2 + w3);
        acc0 = fmaf(w0, (float)t0[4], acc0); acc0 = fmaf(w1, (float)t1[4], acc0);
        acc0 = fmaf(w2, (float)t2[4], acc0); acc0 = fmaf(w3, (float)t3[4], acc0);
        acc1 = fmaf(w0, (float)t0[5], acc1); acc1 = fmaf(w1, (float)t1[5], acc1);
        acc1 = fmaf(w2, (float)t2[5], acc1); acc1 = fmaf(w3, (float)t3[5], acc1);
        acc2 = fmaf(w0, (float)t0[6], acc2); acc2 = fmaf(w1, (float)t1[6], acc2);
        acc2 = fmaf(w2, (float)t2[6], acc2); acc2 = fmaf(w3, (float)t3[6], acc2);
        acc3 = fmaf(w0, (float)t0[7], acc3); acc3 = fmaf(w1, (float)t1[7], acc3);
        acc3 = fmaf(w2, (float)t2[7], acc3); acc3 = fmaf(w3, (float)t3[7], acc3);
    }

    float invd = 1.f / ((float)dd + EPSF);
    f16x8 sf = sfa + sfb;
    float z0 = leaky((float)pt[0] + (float)se[0] + (float)sf[0] * invd) * (float)vc[0];
    float z1 = leaky((float)pt[1] + (float)se[1] + (float)sf[1] * invd) * (float)vc[1];
    float z2 = leaky((float)pt[2] + (float)se[2] + (float)sf[2] * invd) * (float)vc[2];
    float z3 = leaky((float)pt[3] + (float)se[3] + (float)sf[3] * invd) * (float)vc[3];
    float vs = (z0 + z1) + (z2 + z3);
    vs += __shfl_xor(vs, 1, 64);
    vs += __shfl_xor(vs, 2, 64);
    float ws = __expf(vs);
    s += ws;
    acc0 = fmaf(ws, (float)se[4] + (float)sf[4] * invd, acc0);
    acc1 = fmaf(ws, (float)se[5] + (float)sf[5] * invd, acc1);
    acc2 = fmaf(ws, (float)se[6] + (float)sf[6] * invd, acc2);
    acc3 = fmaf(ws, (float)se[7] + (float)sf[7] * invd, acc3);

    float inv = 1.f / (s + EPSF);
    f16x4 res = *(const f16x4*)(Erow + 384 + 4 * sl);
    float o0 = fmaxf((float)res[0] + acc0 * inv, 0.f);
    float o1 = fmaxf((float)res[1] + acc1 * inv, 0.f);
    float o2 = fmaxf((float)res[2] + acc2 * inv, 0.f);
    float o3 = fmaxf((float)res[3] + acc3 * inv, 0.f);
    if (!FINAL) {
        f16x4 o = { (_Float16)o0, (_Float16)o1, (_Float16)o2, (_Float16)o3 };
        *(f16x4*)((_Float16*)xout + (size_t)n * 128 + 4 * sl) = o;
    } else {
        __shared__ float xs[8][132];
        int nib = threadIdx.x >> 5;
        *(float4*)&xs[nib][4 * sl] = make_float4(o0, o1, o2, o3);
        __syncthreads();
        int nn = threadIdx.x >> 5, j = threadIdx.x & 31;
        float a = b2[j];
        const float* xr_ = xs[nn];
#pragma unroll 8
        for (int k = 0; k < 128; k += 4) {
            float4 xv = *(const float4*)&xr_[k];
            a = fmaf(xv.x, W2Tf[(k + 0) * 32 + j], a);
            a = fmaf(xv.y, W2Tf[(k + 1) * 32 + j], a);
            a = fmaf(xv.z, W2Tf[(k + 2) * 32 + j], a);
            a = fmaf(xv.w, W2Tf[(k + 3) * 32 + j], a);
        }
        outp[(size_t)(blockIdx.x * 8 + nn) * 32 + j] = a;
    }
}

// ---------------------------------------------------------------- launch
extern "C" void kernel_launch(void* const* d_in, const int* in_sizes, int n_in,
                              void* d_out, int out_size, void* d_ws, size_t ws_size,
                              hipStream_t stream) {
    const float* emb_ent      = (const float*)d_in[0];
    const float* emb_rel      = (const float*)d_in[1];
    const int*   tr           = (const int*)d_in[2];
    const int*   rt           = (const int*)d_in[3];
    const float* ent_proj1_W  = (const float*)d_in[4];
    const float* ent_proj1_b  = (const float*)d_in[5];
    const float* rel_proj1_W  = (const float*)d_in[6];
    const float* rel_proj1_b  = (const float*)d_in[7];
    const float* rel_attn_W   = (const float*)d_in[8];
    const float* rel_attn_b   = (const float*)d_in[9];
    const float* rel_attn_bin = (const float*)d_in[10];
    const float* rel_attn_vec = (const float*)d_in[11];
    const float* rel_aggr_W   = (const float*)d_in[12];
    const float* rel_aggr_b   = (const float*)d_in[13];
    const float* res_rel_W    = (const float*)d_in[14];
    const float* res_rel_b    = (const float*)d_in[15];
    const float* ent_attn_W   = (const float*)d_in[16];
    const float* ent_attn_b   = (const float*)d_in[17];
    const float* ent_attn_vec = (const float*)d_in[18];
    const float* ent_aggr_W   = (const float*)d_in[19];
    const float* ent_aggr_b   = (const float*)d_in[20];
    const float* res_ent_W    = (const float*)d_in[21];
    const float* res_ent_b    = (const float*)d_in[22];
    const float* ent_proj2_W  = (const float*)d_in[23];
    const float* ent_proj2_b  = (const float*)d_in[24];
    const float* rel_proj2_W  = (const float*)d_in[25];
    const float* rel_proj2_b  = (const float*)d_in[26];
    float* out = (float*)d_out;

    size_t off = 0;
    char* base = (char*)d_ws;
    auto alloc = [&](size_t nbytes) -> void* {
        void* p = base + off;
        off += (nbytes + 255) & ~(size_t)255;
        return p;
    };
    _Float16* embh   = (_Float16*)alloc((size_t)MPE * 32 * 2);
    __half*   xeb    = (__half*)alloc((size_t)MPE * 128 * 2);
    __half*   E16    = (__half*)alloc((size_t)MPE * 512 * 2);
    __half*   R512   = (__half*)alloc((size_t)512 * 512 * 2);
    float*    AR     = (float*)alloc((size_t)N_REL * 256 * 4);
    float*    AR2    = (float*)alloc((size_t)N_REL * 256 * 4);
    _Float16* Bp1f   = (_Float16*)alloc((size_t)512 * 128 * 2);
    float*    bias1  = (float*)alloc(512 * 4);
    _Float16* Bp2f   = (_Float16*)alloc(512 * 64 * 2);
    float*    Bp3    = (float*)alloc((size_t)256 * 64 * 4);
    float*    bias3  = (float*)alloc(256 * 4);
    _Float16* Wcomph = (_Float16*)alloc(512 * 32 * 2);
    float*    biasC  = (float*)alloc(512 * 4);
    float*    W2Tf   = (float*)alloc(128 * 32 * 4);
    _Float16* vech   = (_Float16*)alloc(2 * 128 * 2);
    int*  cnt   = (int*)alloc((size_t)(N_ENT + N_REL) * 4);
    int*  cntE  = cnt;
    int*  cntR  = cnt + N_ENT;
    int2* hrE   = (int2*)alloc((size_t)N_ENT * CAPE * 8);
    int2* tbR   = (int2*)alloc((size_t)N_REL * CAPR * 8);

    // 1. pack + compose + direct AR (LDS-hoisted) + zero counters
    k_pack_all<<<640, 256, 0, stream>>>(
        emb_ent, emb_rel,
        ent_attn_W, ent_attn_b, ent_aggr_W, ent_aggr_b, res_ent_W, res_ent_b,
        rel_attn_W, rel_attn_b, rel_aggr_W, rel_aggr_b, res_rel_W, res_rel_b,
        ent_proj1_W, ent_proj1_b, rel_proj1_W, rel_proj1_b,
        ent_proj2_W, ent_attn_vec,
        embh, Bp1f, bias1, Bp2f, Bp3, bias3,
        Wcomph, biasC, AR, W2Tf, vech, cnt);

    // 2. direct bucket scatter (count + scatter fused, no scan)
    k_scatter_direct<<<(NE + NER + 255) / 256, 256, 0, stream>>>(
        tr, rt, cntE, cntR, hrE, tbR);

    // 3. rel layer 0 (epilogue computes AR2 = x @ Bp3_l1^T + bias3)
    k_rel_fused<0><<<N_REL, 256, 0, stream>>>(
        AR, rel_attn_vec, rel_attn_bin, tbR, cntR,
        Bp3, bias3, AR2, nullptr, nullptr, nullptr, nullptr, nullptr);

    // 4. rel layer 1 (FINAL: R512 + rel output projection)
    k_rel_fused<1><<<N_REL, 256, 0, stream>>>(
        AR2, rel_attn_vec + 64, rel_attn_bin + 80, tbR, cntR,
        nullptr, nullptr, nullptr,
        Bp2f, R512, rel_proj2_W, rel_proj2_b, out + (size_t)N_ENT * 32);

    // 5. ent layer 0 input GEMM (proj1 composed: K=32)
    k_hgemm<<<dim3(8, 157), 256, 0, stream>>>(
        embh, Wcomph, biasC, E16, nullptr, N_ENT, 512, 32, 512);

    // 6. ent layer 0
    k_ent_fused<0><<<(N_ENT / 2 * 64) / 256, 256, 0, stream>>>(
        E16, R512, vech, hrE, cntE, xeb, nullptr, nullptr, nullptr);

    // 7. ent layer 1 input GEMM (K=128)
    k_hgemm<<<dim3(8, 157), 256, 0, stream>>>(
        (const _Float16*)xeb, Bp1f, bias1, E16, nullptr, N_ENT, 512, 128, 512);

    // 8. ent layer 1 (FINAL: fused ent output projection)
    k_ent_fused<1><<<(N_ENT / 2 * 64) / 256, 256, 0, stream>>>(
        E16, R512 + 256, vech + 128, hrE, cntE, nullptr,
        W2Tf, ent_proj2_b, out);
}